// Round 9
// baseline (292.780 us; speedup 1.0000x reference)
//
#include <hip/hip_runtime.h>
#include <hip/hip_fp8.h>

#define N_NODES 50000
#define N_EDGES 600000
#define DH 128
#define DOUT 64
#define NG 64
#define SLOPE 0.2f
#define LB 391          // GEMM blocks: (N_NODES+127)/128
#define SCAN_BLOCKS 25

using short8  = __attribute__((ext_vector_type(8))) short;
using floatx4 = __attribute__((ext_vector_type(4))) float;

__device__ __forceinline__ float leaky(float v){ return fmaxf(v, SLOPE*v); }
__device__ __forceinline__ unsigned f2bf(float x){
  unsigned u = __float_as_uint(x);
  return (u + 0x7fffu + ((u>>16)&1u)) >> 16;          // RNE bf16
}
#if __has_builtin(__builtin_amdgcn_cvt_pk_bf16_f32)
__device__ __forceinline__ unsigned pack2bf(float a, float b){
  auto t = __builtin_amdgcn_cvt_pk_bf16_f32(a, b);
  unsigned u; __builtin_memcpy(&u, &t, 4); return u;
}
#else
__device__ __forceinline__ unsigned pack2bf(float a, float b){
  return f2bf(a) | (f2bf(b) << 16);
}
#endif
__device__ __forceinline__ float bf_lo(unsigned u){ return __uint_as_float(u<<16); }
__device__ __forceinline__ float bf_hi(unsigned u){ return __uint_as_float(u & 0xffff0000u); }

// fp8 e4m3 (OCP, gfx950-native) pack/unpack: hp rows stored as fp8 -> gather bytes halve
#if __has_builtin(__builtin_amdgcn_cvt_pk_fp8_f32) && __has_builtin(__builtin_amdgcn_cvt_pk_f32_fp8)
__device__ __forceinline__ unsigned pack4fp8(float a, float b, float c, float d){
  int v = __builtin_amdgcn_cvt_pk_fp8_f32(a, b, 0, false);
  v = __builtin_amdgcn_cvt_pk_fp8_f32(c, d, v, true);
  return (unsigned)v;
}
__device__ __forceinline__ void dec4fp8(unsigned u, float* f){
  auto lo = __builtin_amdgcn_cvt_pk_f32_fp8((int)u, false);
  auto hi = __builtin_amdgcn_cvt_pk_f32_fp8((int)u, true);
  f[0]=lo[0]; f[1]=lo[1]; f[2]=hi[0]; f[3]=hi[1];
}
#else
__device__ __forceinline__ unsigned pack4fp8(float a, float b, float c, float d){
  __hip_fp8_e4m3 qa(a), qb(b), qc(c), qd(d);
  return (unsigned)qa.__x | ((unsigned)qb.__x<<8) | ((unsigned)qc.__x<<16) | ((unsigned)qd.__x<<24);
}
__device__ __forceinline__ void dec4fp8(unsigned u, float* f){
  __hip_fp8_e4m3 q;
  q.__x=(__hip_fp8_storage_t)(u&0xff);       f[0]=(float)q;
  q.__x=(__hip_fp8_storage_t)((u>>8)&0xff);  f[1]=(float)q;
  q.__x=(__hip_fp8_storage_t)((u>>16)&0xff); f[2]=(float)q;
  q.__x=(__hip_fp8_storage_t)((u>>24)&0xff); f[3]=(float)q;
}
#endif

__device__ __forceinline__ int ld_acq(int* p){
  return __hip_atomic_load(p, __ATOMIC_ACQUIRE, __HIP_MEMORY_SCOPE_AGENT);
}
__device__ __forceinline__ void st_rel(int* p, int v){
  __hip_atomic_store(p, v, __ATOMIC_RELEASE, __HIP_MEMORY_SCOPE_AGENT);
}

// ---------------- CSR build + weight prep + pooled zero (R5-proven) --------------------
// NOTE (R7 lesson): do NOT self-cast W fp32->LDS-transposed inside the GEMM (scalar
// ushort stores at stride 272B = 16-way bank conflict, 3.4M conflicts, K1 46us).
__global__ __launch_bounds__(256)
void k_hist(const int* __restrict__ dst, int* __restrict__ counts,
            int* __restrict__ rank,
            const float* __restrict__ W1, const float* __restrict__ Wg,
            unsigned short* __restrict__ Wt, float* __restrict__ pooled){
  int gid = blockIdx.x*256 + threadIdx.x;
  if (gid < 4*16384){                          // weight prep rides along
    int mi = gid >> 14, r = gid & 16383;
    int k = r >> 7, n = r & 127;
    const float* src = (mi==0) ? W1 : (Wg + (size_t)(mi-1)*16384);
    Wt[(size_t)mi*16384 + (size_t)n*128 + k] = (unsigned short)f2bf(src[k*128 + n]);
  }
  if (gid < NG*DH) pooled[gid] = 0.f;          // pool accumulator zero rides along
  int stride = gridDim.x*256;
  for (int e = gid; e < N_EDGES; e += stride){
    rank[e] = atomicAdd(&counts[dst[e]], 1);
  }
}

// ---------------- MFMA GEMM body (transposed D), fused es/ed ---------------------------
// 512 thr / 8 waves / 128 nodes per block. Wt: [n][k] bf16 staged in LDS (+8 pad).
// OUT8: output stored fp8 e4m3 (gather payload); else bf16 (residual stream).
template<bool AFP32, bool OUT8>
__device__ __forceinline__
void lin_body(const void* __restrict__ Av,
              const unsigned short* __restrict__ Wt,
              const float* __restrict__ bias,
              const float* __restrict__ avs, const float* __restrict__ avd,
              void* __restrict__ outV,
              float* __restrict__ es, float* __restrict__ ed, int nrows,
              int bid, unsigned short* wlds){
  int tid = threadIdx.x;
  #pragma unroll
  for (int i=0;i<4;i++){
    int flat = i*4096 + tid*8;
    int n = flat >> 7, kb = flat & 127;
    *(short8*)&wlds[n*136 + kb] = *(const short8*)(Wt + flat);
  }
  __syncthreads();

  int wid = tid >> 6, lane = tid & 63;
  int l15 = lane & 15, quad = lane >> 4;
  int R0 = bid*128 + wid*16;
  int node = R0 + l15;
  int arow = node < nrows ? node : nrows-1;

  floatx4 acc[8];
  #pragma unroll
  for (int nt=0;nt<8;nt++){ acc[nt][0]=0.f; acc[nt][1]=0.f; acc[nt][2]=0.f; acc[nt][3]=0.f; }

  #pragma unroll
  for (int k0=0;k0<128;k0+=32){
    short8 a;                                   // node fragment (B operand)
    if (AFP32){
      const float* Ap = (const float*)Av + (size_t)arow*128 + quad*8 + k0;
      float4 v0 = *(const float4*)Ap;
      float4 v1 = *(const float4*)(Ap+4);
      union { short8 s; unsigned u[4]; } cv;
      cv.u[0]=pack2bf(v0.x,v0.y); cv.u[1]=pack2bf(v0.z,v0.w);
      cv.u[2]=pack2bf(v1.x,v1.y); cv.u[3]=pack2bf(v1.z,v1.w);
      a = cv.s;
    } else {
      a = *(const short8*)((const unsigned short*)Av + (size_t)arow*128 + quad*8 + k0);
    }
    const unsigned short* bp = &wlds[l15*136 + quad*8 + k0];
    #pragma unroll
    for (int nt=0;nt<8;nt++){
      short8 b = *(const short8*)(bp + nt*16*136);   // Wt fragment (A operand)
      acc[nt] = __builtin_amdgcn_mfma_f32_16x16x32_bf16(b, a, acc[nt], 0,0,0);
    }
  }

  bool nv = node < nrows;
  float ps = 0.f, pd = 0.f;
  #pragma unroll
  for (int nt=0;nt<8;nt++){
    int f0 = nt*16 + quad*4;                  // 4 consecutive features for this lane
    float4 bb = make_float4(0.f,0.f,0.f,0.f);
    if (bias) bb = *(const float4*)(bias + f0);
    float v0 = acc[nt][0]+bb.x, v1 = acc[nt][1]+bb.y;
    float v2 = acc[nt][2]+bb.z, v3 = acc[nt][3]+bb.w;
    if (es){
      float4 a4 = *(const float4*)(avs + f0);
      float4 d4 = *(const float4*)(avd + f0);
      ps = fmaf(v0,a4.x, fmaf(v1,a4.y, fmaf(v2,a4.z, fmaf(v3,a4.w, ps))));
      pd = fmaf(v0,d4.x, fmaf(v1,d4.y, fmaf(v2,d4.z, fmaf(v3,d4.w, pd))));
    }
    if (nv){
      if constexpr (OUT8){
        *(unsigned*)((char*)outV + (size_t)node*128 + f0) = pack4fp8(v0,v1,v2,v3);
      } else {
        uint2 pk; pk.x = pack2bf(v0,v1); pk.y = pack2bf(v2,v3);
        *(uint2*)((unsigned short*)outV + (size_t)node*128 + f0) = pk;
      }
    }
  }
  if (es){
    ps += __shfl_xor(ps, 16, 64); ps += __shfl_xor(ps, 32, 64);
    pd += __shfl_xor(pd, 16, 64); pd += __shfl_xor(pd, 32, 64);
    if (quad==0 && nv){ es[node]=ps; ed[node]=pd; }
  }
}

template<bool AFP32, bool OUT8>
__global__ __launch_bounds__(512)
void k_linear_mfma(const void* __restrict__ Av,
                   const unsigned short* __restrict__ Wt,
                   const float* __restrict__ bias,
                   const float* __restrict__ avs, const float* __restrict__ avd,
                   void* __restrict__ outV,
                   float* __restrict__ es, float* __restrict__ ed, int nrows){
  __shared__ unsigned short wlds[128*136];
  lin_body<AFP32,OUT8>(Av, Wt, bias, avs, avd, outV, es, ed, nrows, blockIdx.x, wlds);
}

// ---------------- fat kernel: mlp1 GEMM (blocks <LB) ∥ FULL row_ptr scan (>=LB) --------
__global__ __launch_bounds__(512)
void k_lin1_scan(const float* __restrict__ x, const unsigned short* __restrict__ Wt,
                 const float* __restrict__ b1, unsigned short* __restrict__ hbf,
                 const int* __restrict__ counts, int* __restrict__ bsum,
                 int* __restrict__ row_ptr){
  __shared__ unsigned short wlds[128*136];
  if ((int)blockIdx.x >= LB){
    int* sb1 = (int*)wlds;          // reuse GEMM LDS: 512 ints scan + 33 ints lookback
    int* lk  = sb1 + 512;
    int sbid = blockIdx.x - LB;     // 0..24
    int t = threadIdx.x;
    int base = sbid*2048;
    int c[4]; int s=0;
    int idx0 = base + t*4;
    #pragma unroll
    for (int j=0;j<4;j++){ int idx = idx0+j; c[j] = (idx<N_NODES)? counts[idx]:0; s += c[j]; }
    sb1[t]=s; __syncthreads();
    for (int off=1; off<512; off<<=1){
      int v = (t>=off)? sb1[t-off] : 0;
      __syncthreads();
      sb1[t]+=v;
      __syncthreads();
    }
    int pre   = sb1[t]-s;           // exclusive prefix within this scan block
    int total = sb1[511];           // block aggregate
    if (t==0){ __threadfence(); st_rel(&bsum[sbid], total+1); }   // publish (flag: +1)
    int lv = 0;
    if (t < sbid){                  // lookback: spin only on LOWER block IDs
      int v;
      do { v = ld_acq(&bsum[t]); } while (v == 0);
      lv = v - 1;
    }
    if (t < 32) lk[t] = lv;
    __syncthreads();
    if (t==0){ int b=0; for (int q=0;q<sbid;q++) b += lk[q]; lk[32]=b; }
    __syncthreads();
    int boff = lk[32];
    int run = pre + boff;
    #pragma unroll
    for (int j=0;j<4;j++){
      int idx = idx0+j;
      if (idx < N_NODES){ row_ptr[idx] = run; run += c[j]; }
    }
    if (sbid == SCAN_BLOCKS-1 && t == 0) row_ptr[N_NODES] = boff + total;  // == N_EDGES
    return;
  }
  lin_body<true,false>(x, Wt, b1, nullptr, nullptr, hbf, nullptr, nullptr, N_NODES,
                       blockIdx.x, wlds);
}

// ---------------- fat kernel: layer-0 GEMM (blocks <LB) ∥ CSR scatter (blocks >=LB) ----
__global__ __launch_bounds__(512)
void k_lin_scatter(const unsigned short* __restrict__ hbf,
                   const unsigned short* __restrict__ Wt,
                   const float* __restrict__ avs, const float* __restrict__ avd,
                   void* __restrict__ hp,
                   float* __restrict__ es, float* __restrict__ ed,
                   const int* __restrict__ esrc, const int* __restrict__ edst,
                   const int* __restrict__ rank, const int* __restrict__ row_ptr,
                   int* __restrict__ col_src){
  if ((int)blockIdx.x >= LB){
    int e0 = (blockIdx.x - LB)*512 + threadIdx.x;
    const int stride = (1024 - LB)*512;
    for (int e = e0; e < N_EDGES; e += stride){
      col_src[row_ptr[edst[e]] + rank[e]] = esrc[e];
    }
    return;
  }
  __shared__ unsigned short wlds[128*136];
  lin_body<false,true>(hbf, Wt, nullptr, avs, avd, hp, es, ed, N_NODES, blockIdx.x, wlds);
}

// ---------------- GAT aggregation: fp8 rows, UNIFORM 16-edge super-groups (R9) ---------
// R8 lesson: the 4-deep loop needed lenp>=16 and deg~Poisson(12) means most nodes ran
// the SERIAL 1-group tail (3 dependent load rounds) -> unroll never engaged. R9: pad
// every chunk to a whole 16-edge super-group; padded slots have w=0/s=0 (row-0 load is
// an L1-resident broadcast line, fmaf(0,..) is a no-op). Every node now issues its 4
// gathers back-to-back -> 1 latency exposure instead of ~3.
#define AGG_BLOCKS 3126
__global__ __launch_bounds__(256)
void k_gat_agg(const uint2* __restrict__ hp8, const float* __restrict__ es,
               const float* __restrict__ ed, const int* __restrict__ row_ptr,
               const int* __restrict__ col_src, const float* __restrict__ bg,
               unsigned* __restrict__ hbf2){
  int lane = threadIdx.x & 63;
  int sub = lane & 15, quad = lane >> 4;
  int subw = sub << 2;                          // bf16 word offset (residual stream)
  int wav0 = blockIdx.x*4 + (threadIdx.x >> 6);
  const int NW = AGG_BLOCKS*4;

  int i = wav0;
  int start=0, end=0; float esi=0.f, edi=0.f;
  if (i < N_NODES){
    start = row_ptr[i]; end = row_ptr[i+1];
    esi = es[i]; edi = ed[i];
  }
  while (i < N_NODES){
    int inext = i + NW;
    int nstart=0, nend=0; float nes=0.f, ned=0.f;
    if (inext < N_NODES){                       // prefetch next node's scalars
      nstart = row_ptr[inext]; nend = row_ptr[inext+1];
      nes = es[inext]; ned = ed[inext];
    }
    float m0 = leaky(esi + edi);                // self score: softmax recentering
    float acc[8];
    if (quad == 0){                             // self weight exp(0)=1, quad0 only
      uint2 u = hp8[(unsigned)i*16u + sub];
      dec4fp8(u.x, acc); dec4fp8(u.y, acc+4);
    } else {
      #pragma unroll
      for (int r=0;r<8;r++) acc[r]=0.f;
    }
    float zl = (lane==0) ? 1.f : 0.f;

    for (int c0 = start; c0 < end; c0 += 64){
      int j = c0 + lane;
      bool valid = j < end;
      int sreg = valid ? col_src[j] : 0;
      float e = leaky(es[sreg] + edi);
      float w = valid ? __expf(e - m0) : 0.f;   // invalid lanes: w=0, s=0 (pad-safe)
      zl += w;
      int len = end - c0; if (len > 64) len = 64;
      int lenp = (len + 15) & ~15;              // pad to whole 16-edge super-groups
      for (int t = 0; t < lenp; t += 16){       // ALWAYS 4 gathers in flight
        int iA = t + quad,      iB = t + 4 + quad;
        int iC = t + 8 + quad,  iD = t + 12 + quad;   // all < 64 (lenp <= 64)
        int   sA = __shfl(sreg, iA, 64),  sB = __shfl(sreg, iB, 64);
        int   sC = __shfl(sreg, iC, 64),  sD = __shfl(sreg, iD, 64);
        float wA = __shfl(w,    iA, 64),  wB = __shfl(w,    iB, 64);
        float wC = __shfl(w,    iC, 64),  wD = __shfl(w,    iD, 64);
        uint2 uA = hp8[(unsigned)sA*16u + sub];
        uint2 uB = hp8[(unsigned)sB*16u + sub];
        uint2 uC = hp8[(unsigned)sC*16u + sub];
        uint2 uD = hp8[(unsigned)sD*16u + sub];
        float fA[8]; dec4fp8(uA.x, fA); dec4fp8(uA.y, fA+4);
        #pragma unroll
        for (int r=0;r<8;r++) acc[r]=fmaf(wA, fA[r], acc[r]);
        float fB[8]; dec4fp8(uB.x, fB); dec4fp8(uB.y, fB+4);
        #pragma unroll
        for (int r=0;r<8;r++) acc[r]=fmaf(wB, fB[r], acc[r]);
        float fC[8]; dec4fp8(uC.x, fC); dec4fp8(uC.y, fC+4);
        #pragma unroll
        for (int r=0;r<8;r++) acc[r]=fmaf(wC, fC[r], acc[r]);
        float fD[8]; dec4fp8(uD.x, fD); dec4fp8(uD.y, fD+4);
        #pragma unroll
        for (int r=0;r<8;r++) acc[r]=fmaf(wD, fD[r], acc[r]);
      }
    }

    // cross-quad reduce: 4 edge-slots accumulated the same feature set
    #pragma unroll
    for (int r=0;r<8;r++){
      acc[r] += __shfl_xor(acc[r], 16, 64);
      acc[r] += __shfl_xor(acc[r], 32, 64);
    }
    float z = zl;
    #pragma unroll
    for (int off=32; off>0; off>>=1) z += __shfl_xor(z, off, 64);
    float inv = 1.f / z;

    if (quad == 0){
      float4 bgA = *(const float4*)(bg + sub*8);
      float4 bgB = *(const float4*)(bg + sub*8 + 4);
      unsigned base = ((unsigned)i<<6) | subw;
      uint4 ho = *(const uint4*)(hbf2 + base);   // residual (bf16 stream)
      float r0 = fmaf(acc[0], inv, bgA.x); r0 = r0>0.f?r0:0.f; r0 += bf_lo(ho.x);
      float r1 = fmaf(acc[1], inv, bgA.y); r1 = r1>0.f?r1:0.f; r1 += bf_hi(ho.x);
      float r2 = fmaf(acc[2], inv, bgA.z); r2 = r2>0.f?r2:0.f; r2 += bf_lo(ho.y);
      float r3 = fmaf(acc[3], inv, bgA.w); r3 = r3>0.f?r3:0.f; r3 += bf_hi(ho.y);
      float r4 = fmaf(acc[4], inv, bgB.x); r4 = r4>0.f?r4:0.f; r4 += bf_lo(ho.z);
      float r5 = fmaf(acc[5], inv, bgB.y); r5 = r5>0.f?r5:0.f; r5 += bf_hi(ho.z);
      float r6 = fmaf(acc[6], inv, bgB.z); r6 = r6>0.f?r6:0.f; r6 += bf_lo(ho.w);
      float r7 = fmaf(acc[7], inv, bgB.w); r7 = r7>0.f?r7:0.f; r7 += bf_hi(ho.w);
      uint4 pk;
      pk.x = pack2bf(r0,r1); pk.y = pack2bf(r2,r3);
      pk.z = pack2bf(r4,r5); pk.w = pack2bf(r6,r7);
      *(uint4*)(hbf2 + base) = pk;
    }
    i = inext; start = nstart; end = nend; esi = nes; edi = ned;
  }
}

// ---------------- global_add_pool (batch sorted -> run accumulate), bf16 in ------------
__global__ __launch_bounds__(256)
void k_pool(const unsigned* __restrict__ hbf2, const int* __restrict__ batch,
            float* __restrict__ pooled){
  int lane = threadIdx.x & 63, w = threadIdx.x >> 6;
  int n0 = blockIdx.x*128 + w*32;
  if (n0 >= N_NODES) return;
  int nEnd = n0 + 32; if (nEnd > N_NODES) nEnd = N_NODES;
  int cur = batch[n0];
  float a0 = 0.f, a1 = 0.f;
  for (int n = n0; n < nEnd; n++){
    int b = batch[n];
    if (b != cur){
      atomicAdd(&pooled[cur*128 + 2*lane],     a0);
      atomicAdd(&pooled[cur*128 + 2*lane + 1], a1);
      a0 = 0.f; a1 = 0.f; cur = b;
    }
    unsigned u = hbf2[((unsigned)n<<6) | lane];
    a0 += bf_lo(u); a1 += bf_hi(u);
  }
  atomicAdd(&pooled[cur*128 + 2*lane],     a0);
  atomicAdd(&pooled[cur*128 + 2*lane + 1], a1);
}

__global__ void k_final(const float* __restrict__ pooled, const float* __restrict__ W2,
                        const float* __restrict__ b2, float* __restrict__ out){
  int gid = blockIdx.x*256 + threadIdx.x;
  if (gid >= NG*DOUT) return;
  int r = gid >> 6, c = gid & 63;
  float acc = b2[c];
  #pragma unroll 4
  for (int k=0;k<DH;k++) acc = fmaf(pooled[r*DH+k], W2[k*DOUT+c], acc);
  out[(size_t)r*DOUT + c] = acc;
}

extern "C" void kernel_launch(void* const* d_in, const int* in_sizes, int n_in,
                              void* d_out, int out_size, void* d_ws, size_t ws_size,
                              hipStream_t stream){
  const float* x     = (const float*)d_in[0];
  const int*   ei    = (const int*)d_in[1];
  const int*   batch = (const int*)d_in[2];
  const float* W1    = (const float*)d_in[3];
  const float* b1    = (const float*)d_in[4];
  const float* Wg    = (const float*)d_in[5];
  const float* avs   = (const float*)d_in[6];
  const float* avd   = (const float*)d_in[7];
  const float* bgv   = (const float*)d_in[8];
  const float* W2    = (const float*)d_in[9];
  const float* b2    = (const float*)d_in[10];
  float* out = (float*)d_out;

  char* ws = (char*)d_ws;
  unsigned short* hbf = (unsigned short*)ws;       ws += (size_t)N_NODES*DH*2;   // residual stream (bf16)
  void* hp        = (void*)ws;                     ws += (size_t)N_NODES*DH;     // GEMM out (fp8 e4m3)
  float* es       = (float*)ws;                    ws += (size_t)N_NODES*4;
  float* ed       = (float*)ws;                    ws += (size_t)N_NODES*4;
  float* pooled   = (float*)ws;                    ws += NG*DH*4;
  unsigned short* Wt = (unsigned short*)ws;        ws += 4*16384*2;
  int* counts     = (int*)ws;                      ws += (size_t)N_NODES*4;      // counts+bsum: one memset
  int* bsum       = (int*)ws;                      ws += 64*4;
  int* row_ptr    = (int*)ws;                      ws += ((size_t)N_NODES+1)*4;
  int* rank       = (int*)ws;                      ws += (size_t)N_EDGES*4;
  int* col_src    = (int*)ws;                      ws += (size_t)N_EDGES*4;

  const int* esrc = ei;
  const int* edst = ei + N_EDGES;

  hipMemsetAsync(counts, 0, (N_NODES + 64)*sizeof(int), stream);

  // K1: edge histogram + weight transpose/cast + pooled zero
  k_hist<<<1024, 256, 0, stream>>>(edst, counts, rank, W1, Wg, Wt, pooled);
  // K2: mlp1 GEMM (391 blocks) ∥ full row_ptr scan via decoupled lookback (25 blocks)
  k_lin1_scan<<<LB + SCAN_BLOCKS, 512, 0, stream>>>(x, Wt, b1, hbf, counts, bsum, row_ptr);
  // K3: layer-0 GEMM + es/ed (391 blocks) ∥ CSR scatter (633 blocks)
  k_lin_scatter<<<1024, 512, 0, stream>>>(hbf, Wt + 16384, avs, avd,
                                          hp, es, ed, esrc, edst, rank, row_ptr, col_src);
  // K4: layer-0 aggregation (fp8 gather, uniform 4-deep super-groups)
  k_gat_agg<<<AGG_BLOCKS, 256, 0, stream>>>((const uint2*)hp, es, ed,
                                            row_ptr, col_src, bgv, (unsigned*)hbf);
  // layers 1,2
  for (int l = 1; l < 3; l++){
    k_linear_mfma<false,true><<<LB, 512, 0, stream>>>(hbf, Wt + (size_t)(l+1)*16384, nullptr,
                                                      avs + l*DH, avd + l*DH,
                                                      hp, es, ed, N_NODES);
    k_gat_agg<<<AGG_BLOCKS, 256, 0, stream>>>((const uint2*)hp, es, ed,
                                              row_ptr, col_src, bgv + l*DH,
                                              (unsigned*)hbf);
  }
  // pool + final linear
  k_pool<<<(N_NODES+127)/128, 256, 0, stream>>>((const unsigned*)hbf, batch, pooled);
  k_final<<<(NG*DOUT+255)/256, 256, 0, stream>>>(pooled, W2, b2, out);
}

// Round 10
// 285.347 us; speedup vs baseline: 1.0260x; 1.0260x over previous
//
#include <hip/hip_runtime.h>
#include <hip/hip_fp8.h>

#define N_NODES 50000
#define N_EDGES 600000
#define DH 128
#define DOUT 64
#define NG 64
#define SLOPE 0.2f
#define LB 391          // GEMM blocks: (N_NODES+127)/128
#define SCAN_BLOCKS 25

using short8  = __attribute__((ext_vector_type(8))) short;
using floatx4 = __attribute__((ext_vector_type(4))) float;

__device__ __forceinline__ float leaky(float v){ return fmaxf(v, SLOPE*v); }
__device__ __forceinline__ unsigned f2bf(float x){
  unsigned u = __float_as_uint(x);
  return (u + 0x7fffu + ((u>>16)&1u)) >> 16;          // RNE bf16
}
#if __has_builtin(__builtin_amdgcn_cvt_pk_bf16_f32)
__device__ __forceinline__ unsigned pack2bf(float a, float b){
  auto t = __builtin_amdgcn_cvt_pk_bf16_f32(a, b);
  unsigned u; __builtin_memcpy(&u, &t, 4); return u;
}
#else
__device__ __forceinline__ unsigned pack2bf(float a, float b){
  return f2bf(a) | (f2bf(b) << 16);
}
#endif
__device__ __forceinline__ float bf_lo(unsigned u){ return __uint_as_float(u<<16); }
__device__ __forceinline__ float bf_hi(unsigned u){ return __uint_as_float(u & 0xffff0000u); }

// fp8 e4m3 (OCP, gfx950-native) pack/unpack: hp rows stored as fp8 -> gather bytes halve
#if __has_builtin(__builtin_amdgcn_cvt_pk_fp8_f32) && __has_builtin(__builtin_amdgcn_cvt_pk_f32_fp8)
__device__ __forceinline__ unsigned pack4fp8(float a, float b, float c, float d){
  int v = __builtin_amdgcn_cvt_pk_fp8_f32(a, b, 0, false);
  v = __builtin_amdgcn_cvt_pk_fp8_f32(c, d, v, true);
  return (unsigned)v;
}
__device__ __forceinline__ void dec4fp8(unsigned u, float* f){
  auto lo = __builtin_amdgcn_cvt_pk_f32_fp8((int)u, false);
  auto hi = __builtin_amdgcn_cvt_pk_f32_fp8((int)u, true);
  f[0]=lo[0]; f[1]=lo[1]; f[2]=hi[0]; f[3]=hi[1];
}
#else
__device__ __forceinline__ unsigned pack4fp8(float a, float b, float c, float d){
  __hip_fp8_e4m3 qa(a), qb(b), qc(c), qd(d);
  return (unsigned)qa.__x | ((unsigned)qb.__x<<8) | ((unsigned)qc.__x<<16) | ((unsigned)qd.__x<<24);
}
__device__ __forceinline__ void dec4fp8(unsigned u, float* f){
  __hip_fp8_e4m3 q;
  q.__x=(__hip_fp8_storage_t)(u&0xff);       f[0]=(float)q;
  q.__x=(__hip_fp8_storage_t)((u>>8)&0xff);  f[1]=(float)q;
  q.__x=(__hip_fp8_storage_t)((u>>16)&0xff); f[2]=(float)q;
  q.__x=(__hip_fp8_storage_t)((u>>24)&0xff); f[3]=(float)q;
}
#endif

__device__ __forceinline__ int ld_acq(int* p){
  return __hip_atomic_load(p, __ATOMIC_ACQUIRE, __HIP_MEMORY_SCOPE_AGENT);
}
__device__ __forceinline__ void st_rel(int* p, int v){
  __hip_atomic_store(p, v, __ATOMIC_RELEASE, __HIP_MEMORY_SCOPE_AGENT);
}

// ---------------- CSR build + weight prep + pooled zero (R5-proven) --------------------
// NOTE (R7 lesson): do NOT self-cast W fp32->LDS-transposed inside the GEMM (scalar
// ushort stores at stride 272B = 16-way bank conflict, 3.4M conflicts, K1 46us).
__global__ __launch_bounds__(256)
void k_hist(const int* __restrict__ dst, int* __restrict__ counts,
            int* __restrict__ rank,
            const float* __restrict__ W1, const float* __restrict__ Wg,
            unsigned short* __restrict__ Wt, float* __restrict__ pooled){
  int gid = blockIdx.x*256 + threadIdx.x;
  if (gid < 4*16384){                          // weight prep rides along
    int mi = gid >> 14, r = gid & 16383;
    int k = r >> 7, n = r & 127;
    const float* src = (mi==0) ? W1 : (Wg + (size_t)(mi-1)*16384);
    Wt[(size_t)mi*16384 + (size_t)n*128 + k] = (unsigned short)f2bf(src[k*128 + n]);
  }
  if (gid < NG*DH) pooled[gid] = 0.f;          // pool accumulator zero rides along
  int stride = gridDim.x*256;
  for (int e = gid; e < N_EDGES; e += stride){
    rank[e] = atomicAdd(&counts[dst[e]], 1);
  }
}

// ---------------- MFMA GEMM body (transposed D), fused es/ed ---------------------------
// 512 thr / 8 waves / 128 nodes per block. Wt: [n][k] bf16 staged in LDS (+8 pad).
// OUT8: output stored fp8 e4m3 (gather payload); else bf16 (residual stream).
template<bool AFP32, bool OUT8>
__device__ __forceinline__
void lin_body(const void* __restrict__ Av,
              const unsigned short* __restrict__ Wt,
              const float* __restrict__ bias,
              const float* __restrict__ avs, const float* __restrict__ avd,
              void* __restrict__ outV,
              float* __restrict__ es, float* __restrict__ ed, int nrows,
              int bid, unsigned short* wlds){
  int tid = threadIdx.x;
  #pragma unroll
  for (int i=0;i<4;i++){
    int flat = i*4096 + tid*8;
    int n = flat >> 7, kb = flat & 127;
    *(short8*)&wlds[n*136 + kb] = *(const short8*)(Wt + flat);
  }
  __syncthreads();

  int wid = tid >> 6, lane = tid & 63;
  int l15 = lane & 15, quad = lane >> 4;
  int R0 = bid*128 + wid*16;
  int node = R0 + l15;
  int arow = node < nrows ? node : nrows-1;

  floatx4 acc[8];
  #pragma unroll
  for (int nt=0;nt<8;nt++){ acc[nt][0]=0.f; acc[nt][1]=0.f; acc[nt][2]=0.f; acc[nt][3]=0.f; }

  #pragma unroll
  for (int k0=0;k0<128;k0+=32){
    short8 a;                                   // node fragment (B operand)
    if (AFP32){
      const float* Ap = (const float*)Av + (size_t)arow*128 + quad*8 + k0;
      float4 v0 = *(const float4*)Ap;
      float4 v1 = *(const float4*)(Ap+4);
      union { short8 s; unsigned u[4]; } cv;
      cv.u[0]=pack2bf(v0.x,v0.y); cv.u[1]=pack2bf(v0.z,v0.w);
      cv.u[2]=pack2bf(v1.x,v1.y); cv.u[3]=pack2bf(v1.z,v1.w);
      a = cv.s;
    } else {
      a = *(const short8*)((const unsigned short*)Av + (size_t)arow*128 + quad*8 + k0);
    }
    const unsigned short* bp = &wlds[l15*136 + quad*8 + k0];
    #pragma unroll
    for (int nt=0;nt<8;nt++){
      short8 b = *(const short8*)(bp + nt*16*136);   // Wt fragment (A operand)
      acc[nt] = __builtin_amdgcn_mfma_f32_16x16x32_bf16(b, a, acc[nt], 0,0,0);
    }
  }

  bool nv = node < nrows;
  float ps = 0.f, pd = 0.f;
  #pragma unroll
  for (int nt=0;nt<8;nt++){
    int f0 = nt*16 + quad*4;                  // 4 consecutive features for this lane
    float4 bb = make_float4(0.f,0.f,0.f,0.f);
    if (bias) bb = *(const float4*)(bias + f0);
    float v0 = acc[nt][0]+bb.x, v1 = acc[nt][1]+bb.y;
    float v2 = acc[nt][2]+bb.z, v3 = acc[nt][3]+bb.w;
    if (es){
      float4 a4 = *(const float4*)(avs + f0);
      float4 d4 = *(const float4*)(avd + f0);
      ps = fmaf(v0,a4.x, fmaf(v1,a4.y, fmaf(v2,a4.z, fmaf(v3,a4.w, ps))));
      pd = fmaf(v0,d4.x, fmaf(v1,d4.y, fmaf(v2,d4.z, fmaf(v3,d4.w, pd))));
    }
    if (nv){
      if constexpr (OUT8){
        *(unsigned*)((char*)outV + (size_t)node*128 + f0) = pack4fp8(v0,v1,v2,v3);
      } else {
        uint2 pk; pk.x = pack2bf(v0,v1); pk.y = pack2bf(v2,v3);
        *(uint2*)((unsigned short*)outV + (size_t)node*128 + f0) = pk;
      }
    }
  }
  if (es){
    ps += __shfl_xor(ps, 16, 64); ps += __shfl_xor(ps, 32, 64);
    pd += __shfl_xor(pd, 16, 64); pd += __shfl_xor(pd, 32, 64);
    if (quad==0 && nv){ es[node]=ps; ed[node]=pd; }
  }
}

template<bool AFP32, bool OUT8>
__global__ __launch_bounds__(512)
void k_linear_mfma(const void* __restrict__ Av,
                   const unsigned short* __restrict__ Wt,
                   const float* __restrict__ bias,
                   const float* __restrict__ avs, const float* __restrict__ avd,
                   void* __restrict__ outV,
                   float* __restrict__ es, float* __restrict__ ed, int nrows){
  __shared__ unsigned short wlds[128*136];
  lin_body<AFP32,OUT8>(Av, Wt, bias, avs, avd, outV, es, ed, nrows, blockIdx.x, wlds);
}

// ---------------- fat kernel: mlp1 GEMM (blocks <LB) ∥ FULL row_ptr scan (>=LB) --------
__global__ __launch_bounds__(512)
void k_lin1_scan(const float* __restrict__ x, const unsigned short* __restrict__ Wt,
                 const float* __restrict__ b1, unsigned short* __restrict__ hbf,
                 const int* __restrict__ counts, int* __restrict__ bsum,
                 int* __restrict__ row_ptr){
  __shared__ unsigned short wlds[128*136];
  if ((int)blockIdx.x >= LB){
    int* sb1 = (int*)wlds;          // reuse GEMM LDS: 512 ints scan + 33 ints lookback
    int* lk  = sb1 + 512;
    int sbid = blockIdx.x - LB;     // 0..24
    int t = threadIdx.x;
    int base = sbid*2048;
    int c[4]; int s=0;
    int idx0 = base + t*4;
    #pragma unroll
    for (int j=0;j<4;j++){ int idx = idx0+j; c[j] = (idx<N_NODES)? counts[idx]:0; s += c[j]; }
    sb1[t]=s; __syncthreads();
    for (int off=1; off<512; off<<=1){
      int v = (t>=off)? sb1[t-off] : 0;
      __syncthreads();
      sb1[t]+=v;
      __syncthreads();
    }
    int pre   = sb1[t]-s;           // exclusive prefix within this scan block
    int total = sb1[511];           // block aggregate
    if (t==0){ __threadfence(); st_rel(&bsum[sbid], total+1); }   // publish (flag: +1)
    int lv = 0;
    if (t < sbid){                  // lookback: spin only on LOWER block IDs
      int v;
      do { v = ld_acq(&bsum[t]); } while (v == 0);
      lv = v - 1;
    }
    if (t < 32) lk[t] = lv;
    __syncthreads();
    if (t==0){ int b=0; for (int q=0;q<sbid;q++) b += lk[q]; lk[32]=b; }
    __syncthreads();
    int boff = lk[32];
    int run = pre + boff;
    #pragma unroll
    for (int j=0;j<4;j++){
      int idx = idx0+j;
      if (idx < N_NODES){ row_ptr[idx] = run; run += c[j]; }
    }
    if (sbid == SCAN_BLOCKS-1 && t == 0) row_ptr[N_NODES] = boff + total;  // == N_EDGES
    return;
  }
  lin_body<true,false>(x, Wt, b1, nullptr, nullptr, hbf, nullptr, nullptr, N_NODES,
                       blockIdx.x, wlds);
}

// ---------------- fat kernel: layer-0 GEMM (blocks <LB) ∥ CSR scatter (blocks >=LB) ----
__global__ __launch_bounds__(512)
void k_lin_scatter(const unsigned short* __restrict__ hbf,
                   const unsigned short* __restrict__ Wt,
                   const float* __restrict__ avs, const float* __restrict__ avd,
                   void* __restrict__ hp,
                   float* __restrict__ es, float* __restrict__ ed,
                   const int* __restrict__ esrc, const int* __restrict__ edst,
                   const int* __restrict__ rank, const int* __restrict__ row_ptr,
                   int* __restrict__ col_src){
  if ((int)blockIdx.x >= LB){
    int e0 = (blockIdx.x - LB)*512 + threadIdx.x;
    const int stride = (1024 - LB)*512;
    for (int e = e0; e < N_EDGES; e += stride){
      col_src[row_ptr[edst[e]] + rank[e]] = esrc[e];
    }
    return;
  }
  __shared__ unsigned short wlds[128*136];
  lin_body<false,true>(hbf, Wt, nullptr, avs, avd, hp, es, ed, N_NODES, blockIdx.x, wlds);
}

// ---------------- per-edge source-score gather: ese[j] = es[col_src[j]] ----------------
// R10: lifts the 64-lane DIVERGENT es gather (up to 64 cache lines per node, ~3.2M L2
// line transactions per layer — more than the hp row-gather itself) out of agg into a
// latency-tolerant throughput kernel. agg then reads ese[] coalesced. ed[i] is already
// wave-local in agg, so only es needs lifting; leaky applied in-agg.
__global__ __launch_bounds__(256)
void k_edge_ese(const float* __restrict__ es, const int* __restrict__ col_src,
                float* __restrict__ ese){
  int stride = gridDim.x*256;
  for (int j = blockIdx.x*256 + threadIdx.x; j < N_EDGES; j += stride){
    ese[j] = es[col_src[j]];
  }
}

// ---------------- GAT aggregation: fp8 rows, coalesced ese, 2-group gather (R5 loop) ---
// Chunk front-end: {col_src[j], ese[j]} parallel coalesced loads -> leaky+exp -> shfl ->
// fp8 row gather. R5's 2-group loop restored (best measured; R8/R9 deeper unrolls null
// or negative — TLP at ~12 waves/SIMD already hides per-wave latency).
#define AGG_BLOCKS 3126
__global__ __launch_bounds__(256)
void k_gat_agg(const uint2* __restrict__ hp8, const float* __restrict__ es,
               const float* __restrict__ ed, const int* __restrict__ row_ptr,
               const int* __restrict__ col_src, const float* __restrict__ ese,
               const float* __restrict__ bg, unsigned* __restrict__ hbf2){
  int lane = threadIdx.x & 63;
  int sub = lane & 15, quad = lane >> 4;
  int subw = sub << 2;                          // bf16 word offset (residual stream)
  int wav0 = blockIdx.x*4 + (threadIdx.x >> 6);
  const int NW = AGG_BLOCKS*4;

  int i = wav0;
  int start=0, end=0; float esi=0.f, edi=0.f;
  if (i < N_NODES){
    start = row_ptr[i]; end = row_ptr[i+1];
    esi = es[i]; edi = ed[i];
  }
  while (i < N_NODES){
    int inext = i + NW;
    int nstart=0, nend=0; float nes=0.f, ned=0.f;
    if (inext < N_NODES){                       // prefetch next node's scalars
      nstart = row_ptr[inext]; nend = row_ptr[inext+1];
      nes = es[inext]; ned = ed[inext];
    }
    float m0 = leaky(esi + edi);                // self score: softmax recentering
    float acc[8];
    if (quad == 0){                             // self weight exp(0)=1, quad0 only
      uint2 u = hp8[(unsigned)i*16u + sub];
      dec4fp8(u.x, acc); dec4fp8(u.y, acc+4);
    } else {
      #pragma unroll
      for (int r=0;r<8;r++) acc[r]=0.f;
    }
    float zl = (lane==0) ? 1.f : 0.f;

    for (int c0 = start; c0 < end; c0 += 64){
      int j = c0 + lane;
      bool valid = j < end;
      int   sreg = valid ? col_src[j] : 0;      // coalesced
      float ej   = valid ? ese[j] : 0.f;        // coalesced, parallel with col_src
      float e = leaky(ej + edi);
      float w = valid ? __expf(e - m0) : 0.f;   // invalid lanes: w=0 (safe in groups)
      zl += w;
      int len = end - c0; if (len > 64) len = 64;
      int lenp = (len + 3) & ~3;                // round up to whole groups of 4
      int t = 0;
      for (; t + 8 <= lenp; t += 8){            // 2 groups in flight
        int iA = t + quad,          iB = t + 4 + quad;
        int   sA = __shfl(sreg, iA, 64),  sB = __shfl(sreg, iB, 64);
        float wA = __shfl(w,    iA, 64),  wB = __shfl(w,    iB, 64);
        uint2 uA = hp8[(unsigned)sA*16u + sub];
        uint2 uB = hp8[(unsigned)sB*16u + sub];
        float fA[8]; dec4fp8(uA.x, fA); dec4fp8(uA.y, fA+4);
        float fB[8]; dec4fp8(uB.x, fB); dec4fp8(uB.y, fB+4);
        #pragma unroll
        for (int r=0;r<8;r++) acc[r]=fmaf(wA, fA[r], acc[r]);
        #pragma unroll
        for (int r=0;r<8;r++) acc[r]=fmaf(wB, fB[r], acc[r]);
      }
      if (t < lenp){
        int iA = t + quad;
        int   sA = __shfl(sreg, iA, 64);
        float wA = __shfl(w,    iA, 64);
        uint2 uA = hp8[(unsigned)sA*16u + sub];
        float fA[8]; dec4fp8(uA.x, fA); dec4fp8(uA.y, fA+4);
        #pragma unroll
        for (int r=0;r<8;r++) acc[r]=fmaf(wA, fA[r], acc[r]);
      }
    }

    // cross-quad reduce: 4 edge-slots accumulated the same feature set
    #pragma unroll
    for (int r=0;r<8;r++){
      acc[r] += __shfl_xor(acc[r], 16, 64);
      acc[r] += __shfl_xor(acc[r], 32, 64);
    }
    float z = zl;
    #pragma unroll
    for (int off=32; off>0; off>>=1) z += __shfl_xor(z, off, 64);
    float inv = 1.f / z;

    if (quad == 0){
      float4 bgA = *(const float4*)(bg + sub*8);
      float4 bgB = *(const float4*)(bg + sub*8 + 4);
      unsigned base = ((unsigned)i<<6) | subw;
      uint4 ho = *(const uint4*)(hbf2 + base);   // residual (bf16 stream)
      float r0 = fmaf(acc[0], inv, bgA.x); r0 = r0>0.f?r0:0.f; r0 += bf_lo(ho.x);
      float r1 = fmaf(acc[1], inv, bgA.y); r1 = r1>0.f?r1:0.f; r1 += bf_hi(ho.x);
      float r2 = fmaf(acc[2], inv, bgA.z); r2 = r2>0.f?r2:0.f; r2 += bf_lo(ho.y);
      float r3 = fmaf(acc[3], inv, bgA.w); r3 = r3>0.f?r3:0.f; r3 += bf_hi(ho.y);
      float r4 = fmaf(acc[4], inv, bgB.x); r4 = r4>0.f?r4:0.f; r4 += bf_lo(ho.z);
      float r5 = fmaf(acc[5], inv, bgB.y); r5 = r5>0.f?r5:0.f; r5 += bf_hi(ho.z);
      float r6 = fmaf(acc[6], inv, bgB.z); r6 = r6>0.f?r6:0.f; r6 += bf_lo(ho.w);
      float r7 = fmaf(acc[7], inv, bgB.w); r7 = r7>0.f?r7:0.f; r7 += bf_hi(ho.w);
      uint4 pk;
      pk.x = pack2bf(r0,r1); pk.y = pack2bf(r2,r3);
      pk.z = pack2bf(r4,r5); pk.w = pack2bf(r6,r7);
      *(uint4*)(hbf2 + base) = pk;
    }
    i = inext; start = nstart; end = nend; esi = nes; edi = ned;
  }
}

// ---------------- global_add_pool (batch sorted -> run accumulate), bf16 in ------------
__global__ __launch_bounds__(256)
void k_pool(const unsigned* __restrict__ hbf2, const int* __restrict__ batch,
            float* __restrict__ pooled){
  int lane = threadIdx.x & 63, w = threadIdx.x >> 6;
  int n0 = blockIdx.x*128 + w*32;
  if (n0 >= N_NODES) return;
  int nEnd = n0 + 32; if (nEnd > N_NODES) nEnd = N_NODES;
  int cur = batch[n0];
  float a0 = 0.f, a1 = 0.f;
  for (int n = n0; n < nEnd; n++){
    int b = batch[n];
    if (b != cur){
      atomicAdd(&pooled[cur*128 + 2*lane],     a0);
      atomicAdd(&pooled[cur*128 + 2*lane + 1], a1);
      a0 = 0.f; a1 = 0.f; cur = b;
    }
    unsigned u = hbf2[((unsigned)n<<6) | lane];
    a0 += bf_lo(u); a1 += bf_hi(u);
  }
  atomicAdd(&pooled[cur*128 + 2*lane],     a0);
  atomicAdd(&pooled[cur*128 + 2*lane + 1], a1);
}

__global__ void k_final(const float* __restrict__ pooled, const float* __restrict__ W2,
                        const float* __restrict__ b2, float* __restrict__ out){
  int gid = blockIdx.x*256 + threadIdx.x;
  if (gid >= NG*DOUT) return;
  int r = gid >> 6, c = gid & 63;
  float acc = b2[c];
  #pragma unroll 4
  for (int k=0;k<DH;k++) acc = fmaf(pooled[r*DH+k], W2[k*DOUT+c], acc);
  out[(size_t)r*DOUT + c] = acc;
}

extern "C" void kernel_launch(void* const* d_in, const int* in_sizes, int n_in,
                              void* d_out, int out_size, void* d_ws, size_t ws_size,
                              hipStream_t stream){
  const float* x     = (const float*)d_in[0];
  const int*   ei    = (const int*)d_in[1];
  const int*   batch = (const int*)d_in[2];
  const float* W1    = (const float*)d_in[3];
  const float* b1    = (const float*)d_in[4];
  const float* Wg    = (const float*)d_in[5];
  const float* avs   = (const float*)d_in[6];
  const float* avd   = (const float*)d_in[7];
  const float* bgv   = (const float*)d_in[8];
  const float* W2    = (const float*)d_in[9];
  const float* b2    = (const float*)d_in[10];
  float* out = (float*)d_out;

  char* ws = (char*)d_ws;
  unsigned short* hbf = (unsigned short*)ws;       ws += (size_t)N_NODES*DH*2;   // residual stream (bf16)
  void* hp        = (void*)ws;                     ws += (size_t)N_NODES*DH;     // GEMM out (fp8 e4m3)
  float* es       = (float*)ws;                    ws += (size_t)N_NODES*4;
  float* ed       = (float*)ws;                    ws += (size_t)N_NODES*4;
  float* pooled   = (float*)ws;                    ws += NG*DH*4;
  unsigned short* Wt = (unsigned short*)ws;        ws += 4*16384*2;
  int* counts     = (int*)ws;                      ws += (size_t)N_NODES*4;      // counts+bsum: one memset
  int* bsum       = (int*)ws;                      ws += 64*4;
  int* row_ptr    = (int*)ws;                      ws += ((size_t)N_NODES+1)*4;
  int* rank       = (int*)ws;                      ws += (size_t)N_EDGES*4;
  int* col_src    = (int*)ws;                      ws += (size_t)N_EDGES*4;
  float* ese      = (float*)ws;                    ws += (size_t)N_EDGES*4;

  const int* esrc = ei;
  const int* edst = ei + N_EDGES;

  hipMemsetAsync(counts, 0, (N_NODES + 64)*sizeof(int), stream);

  // K1: edge histogram + weight transpose/cast + pooled zero
  k_hist<<<1024, 256, 0, stream>>>(edst, counts, rank, W1, Wg, Wt, pooled);
  // K2: mlp1 GEMM (391 blocks) ∥ full row_ptr scan via decoupled lookback (25 blocks)
  k_lin1_scan<<<LB + SCAN_BLOCKS, 512, 0, stream>>>(x, Wt, b1, hbf, counts, bsum, row_ptr);
  // K3: layer-0 GEMM + es/ed (391 blocks) ∥ CSR scatter (633 blocks)
  k_lin_scatter<<<1024, 512, 0, stream>>>(hbf, Wt + 16384, avs, avd,
                                          hp, es, ed, esrc, edst, rank, row_ptr, col_src);
  // layer-0: ese gather then aggregation
  k_edge_ese<<<1024, 256, 0, stream>>>(es, col_src, ese);
  k_gat_agg<<<AGG_BLOCKS, 256, 0, stream>>>((const uint2*)hp, es, ed,
                                            row_ptr, col_src, ese, bgv, (unsigned*)hbf);
  // layers 1,2
  for (int l = 1; l < 3; l++){
    k_linear_mfma<false,true><<<LB, 512, 0, stream>>>(hbf, Wt + (size_t)(l+1)*16384, nullptr,
                                                      avs + l*DH, avd + l*DH,
                                                      hp, es, ed, N_NODES);
    k_edge_ese<<<1024, 256, 0, stream>>>(es, col_src, ese);
    k_gat_agg<<<AGG_BLOCKS, 256, 0, stream>>>((const uint2*)hp, es, ed,
                                              row_ptr, col_src, ese, bgv + l*DH,
                                              (unsigned*)hbf);
  }
  // pool + final linear
  k_pool<<<(N_NODES+127)/128, 256, 0, stream>>>((const unsigned*)hbf, batch, pooled);
  k_final<<<(NG*DOUT+255)/256, 256, 0, stream>>>(pooled, W2, b2, out);
}

// Round 11
// 278.911 us; speedup vs baseline: 1.0497x; 1.0231x over previous
//
#include <hip/hip_runtime.h>
#include <hip/hip_fp8.h>

#define N_NODES 50000
#define N_EDGES 600000
#define DH 128
#define DOUT 64
#define NG 64
#define SLOPE 0.2f
#define LB 391          // GEMM blocks: (N_NODES+127)/128
#define SCAN_BLOCKS 25

using short8  = __attribute__((ext_vector_type(8))) short;
using floatx4 = __attribute__((ext_vector_type(4))) float;

__device__ __forceinline__ float leaky(float v){ return fmaxf(v, SLOPE*v); }
__device__ __forceinline__ unsigned f2bf(float x){
  unsigned u = __float_as_uint(x);
  return (u + 0x7fffu + ((u>>16)&1u)) >> 16;          // RNE bf16
}
#if __has_builtin(__builtin_amdgcn_cvt_pk_bf16_f32)
__device__ __forceinline__ unsigned pack2bf(float a, float b){
  auto t = __builtin_amdgcn_cvt_pk_bf16_f32(a, b);
  unsigned u; __builtin_memcpy(&u, &t, 4); return u;
}
#else
__device__ __forceinline__ unsigned pack2bf(float a, float b){
  return f2bf(a) | (f2bf(b) << 16);
}
#endif
__device__ __forceinline__ float bf_lo(unsigned u){ return __uint_as_float(u<<16); }
__device__ __forceinline__ float bf_hi(unsigned u){ return __uint_as_float(u & 0xffff0000u); }

// fp8 e4m3 (OCP, gfx950-native) pack/unpack: hp rows stored as fp8 -> gather bytes halve
#if __has_builtin(__builtin_amdgcn_cvt_pk_fp8_f32) && __has_builtin(__builtin_amdgcn_cvt_pk_f32_fp8)
__device__ __forceinline__ unsigned pack4fp8(float a, float b, float c, float d){
  int v = __builtin_amdgcn_cvt_pk_fp8_f32(a, b, 0, false);
  v = __builtin_amdgcn_cvt_pk_fp8_f32(c, d, v, true);
  return (unsigned)v;
}
__device__ __forceinline__ void dec4fp8(unsigned u, float* f){
  auto lo = __builtin_amdgcn_cvt_pk_f32_fp8((int)u, false);
  auto hi = __builtin_amdgcn_cvt_pk_f32_fp8((int)u, true);
  f[0]=lo[0]; f[1]=lo[1]; f[2]=hi[0]; f[3]=hi[1];
}
#else
__device__ __forceinline__ unsigned pack4fp8(float a, float b, float c, float d){
  __hip_fp8_e4m3 qa(a), qb(b), qc(c), qd(d);
  return (unsigned)qa.__x | ((unsigned)qb.__x<<8) | ((unsigned)qc.__x<<16) | ((unsigned)qd.__x<<24);
}
__device__ __forceinline__ void dec4fp8(unsigned u, float* f){
  __hip_fp8_e4m3 q;
  q.__x=(__hip_fp8_storage_t)(u&0xff);       f[0]=(float)q;
  q.__x=(__hip_fp8_storage_t)((u>>8)&0xff);  f[1]=(float)q;
  q.__x=(__hip_fp8_storage_t)((u>>16)&0xff); f[2]=(float)q;
  q.__x=(__hip_fp8_storage_t)((u>>24)&0xff); f[3]=(float)q;
}
#endif

__device__ __forceinline__ int ld_acq(int* p){
  return __hip_atomic_load(p, __ATOMIC_ACQUIRE, __HIP_MEMORY_SCOPE_AGENT);
}
__device__ __forceinline__ void st_rel(int* p, int v){
  __hip_atomic_store(p, v, __ATOMIC_RELEASE, __HIP_MEMORY_SCOPE_AGENT);
}

// ---------------- CSR build + weight prep + pooled zero (R5-proven) --------------------
// Session ledger (do NOT revisit):
//  - pool+final 64-block fusion: 2.2% occupancy, 64us (R1)
//  - WF32 in-GEMM W transpose staging: 16-way LDS bank conflict, 3.4M events (R7)
//  - >2-deep gather unroll / 16-edge padding: null / -14us (R8/R9)
//  - we/ese edge-score precompute: null both times (R7/R10)
//  - multi-hundred-block flag-spin: GPU hang (R6)
__global__ __launch_bounds__(256)
void k_hist(const int* __restrict__ dst, int* __restrict__ counts,
            int* __restrict__ rank,
            const float* __restrict__ W1, const float* __restrict__ Wg,
            unsigned short* __restrict__ Wt, float* __restrict__ pooled){
  int gid = blockIdx.x*256 + threadIdx.x;
  if (gid < 4*16384){                          // weight prep rides along
    int mi = gid >> 14, r = gid & 16383;
    int k = r >> 7, n = r & 127;
    const float* src = (mi==0) ? W1 : (Wg + (size_t)(mi-1)*16384);
    Wt[(size_t)mi*16384 + (size_t)n*128 + k] = (unsigned short)f2bf(src[k*128 + n]);
  }
  if (gid < NG*DH) pooled[gid] = 0.f;          // pool accumulator zero rides along
  int stride = gridDim.x*256;
  for (int e = gid; e < N_EDGES; e += stride){
    rank[e] = atomicAdd(&counts[dst[e]], 1);
  }
}

// ---------------- MFMA GEMM body (transposed D), fused es/ed ---------------------------
// 512 thr / 8 waves / 128 nodes per block. Wt: [n][k] bf16 staged in LDS (+8 pad).
// OUT8: output stored fp8 e4m3 (gather payload); else bf16 (residual stream).
template<bool AFP32, bool OUT8>
__device__ __forceinline__
void lin_body(const void* __restrict__ Av,
              const unsigned short* __restrict__ Wt,
              const float* __restrict__ bias,
              const float* __restrict__ avs, const float* __restrict__ avd,
              void* __restrict__ outV,
              float* __restrict__ es, float* __restrict__ ed, int nrows,
              int bid, unsigned short* wlds){
  int tid = threadIdx.x;
  #pragma unroll
  for (int i=0;i<4;i++){
    int flat = i*4096 + tid*8;
    int n = flat >> 7, kb = flat & 127;
    *(short8*)&wlds[n*136 + kb] = *(const short8*)(Wt + flat);
  }
  __syncthreads();

  int wid = tid >> 6, lane = tid & 63;
  int l15 = lane & 15, quad = lane >> 4;
  int R0 = bid*128 + wid*16;
  int node = R0 + l15;
  int arow = node < nrows ? node : nrows-1;

  floatx4 acc[8];
  #pragma unroll
  for (int nt=0;nt<8;nt++){ acc[nt][0]=0.f; acc[nt][1]=0.f; acc[nt][2]=0.f; acc[nt][3]=0.f; }

  #pragma unroll
  for (int k0=0;k0<128;k0+=32){
    short8 a;                                   // node fragment (B operand)
    if (AFP32){
      const float* Ap = (const float*)Av + (size_t)arow*128 + quad*8 + k0;
      float4 v0 = *(const float4*)Ap;
      float4 v1 = *(const float4*)(Ap+4);
      union { short8 s; unsigned u[4]; } cv;
      cv.u[0]=pack2bf(v0.x,v0.y); cv.u[1]=pack2bf(v0.z,v0.w);
      cv.u[2]=pack2bf(v1.x,v1.y); cv.u[3]=pack2bf(v1.z,v1.w);
      a = cv.s;
    } else {
      a = *(const short8*)((const unsigned short*)Av + (size_t)arow*128 + quad*8 + k0);
    }
    const unsigned short* bp = &wlds[l15*136 + quad*8 + k0];
    #pragma unroll
    for (int nt=0;nt<8;nt++){
      short8 b = *(const short8*)(bp + nt*16*136);   // Wt fragment (A operand)
      acc[nt] = __builtin_amdgcn_mfma_f32_16x16x32_bf16(b, a, acc[nt], 0,0,0);
    }
  }

  bool nv = node < nrows;
  float ps = 0.f, pd = 0.f;
  #pragma unroll
  for (int nt=0;nt<8;nt++){
    int f0 = nt*16 + quad*4;                  // 4 consecutive features for this lane
    float4 bb = make_float4(0.f,0.f,0.f,0.f);
    if (bias) bb = *(const float4*)(bias + f0);
    float v0 = acc[nt][0]+bb.x, v1 = acc[nt][1]+bb.y;
    float v2 = acc[nt][2]+bb.z, v3 = acc[nt][3]+bb.w;
    if (es){
      float4 a4 = *(const float4*)(avs + f0);
      float4 d4 = *(const float4*)(avd + f0);
      ps = fmaf(v0,a4.x, fmaf(v1,a4.y, fmaf(v2,a4.z, fmaf(v3,a4.w, ps))));
      pd = fmaf(v0,d4.x, fmaf(v1,d4.y, fmaf(v2,d4.z, fmaf(v3,d4.w, pd))));
    }
    if (nv){
      if constexpr (OUT8){
        *(unsigned*)((char*)outV + (size_t)node*128 + f0) = pack4fp8(v0,v1,v2,v3);
      } else {
        uint2 pk; pk.x = pack2bf(v0,v1); pk.y = pack2bf(v2,v3);
        *(uint2*)((unsigned short*)outV + (size_t)node*128 + f0) = pk;
      }
    }
  }
  if (es){
    ps += __shfl_xor(ps, 16, 64); ps += __shfl_xor(ps, 32, 64);
    pd += __shfl_xor(pd, 16, 64); pd += __shfl_xor(pd, 32, 64);
    if (quad==0 && nv){ es[node]=ps; ed[node]=pd; }
  }
}

template<bool AFP32, bool OUT8>
__global__ __launch_bounds__(512)
void k_linear_mfma(const void* __restrict__ Av,
                   const unsigned short* __restrict__ Wt,
                   const float* __restrict__ bias,
                   const float* __restrict__ avs, const float* __restrict__ avd,
                   void* __restrict__ outV,
                   float* __restrict__ es, float* __restrict__ ed, int nrows){
  __shared__ unsigned short wlds[128*136];
  lin_body<AFP32,OUT8>(Av, Wt, bias, avs, avd, outV, es, ed, nrows, blockIdx.x, wlds);
}

// ---------------- fat kernel: mlp1 GEMM (blocks <LB) ∥ FULL row_ptr scan (>=LB) --------
__global__ __launch_bounds__(512)
void k_lin1_scan(const float* __restrict__ x, const unsigned short* __restrict__ Wt,
                 const float* __restrict__ b1, unsigned short* __restrict__ hbf,
                 const int* __restrict__ counts, int* __restrict__ bsum,
                 int* __restrict__ row_ptr){
  __shared__ unsigned short wlds[128*136];
  if ((int)blockIdx.x >= LB){
    int* sb1 = (int*)wlds;          // reuse GEMM LDS: 512 ints scan + 33 ints lookback
    int* lk  = sb1 + 512;
    int sbid = blockIdx.x - LB;     // 0..24
    int t = threadIdx.x;
    int base = sbid*2048;
    int c[4]; int s=0;
    int idx0 = base + t*4;
    #pragma unroll
    for (int j=0;j<4;j++){ int idx = idx0+j; c[j] = (idx<N_NODES)? counts[idx]:0; s += c[j]; }
    sb1[t]=s; __syncthreads();
    for (int off=1; off<512; off<<=1){
      int v = (t>=off)? sb1[t-off] : 0;
      __syncthreads();
      sb1[t]+=v;
      __syncthreads();
    }
    int pre   = sb1[t]-s;           // exclusive prefix within this scan block
    int total = sb1[511];           // block aggregate
    if (t==0){ __threadfence(); st_rel(&bsum[sbid], total+1); }   // publish (flag: +1)
    int lv = 0;
    if (t < sbid){                  // lookback: spin only on LOWER block IDs
      int v;
      do { v = ld_acq(&bsum[t]); } while (v == 0);
      lv = v - 1;
    }
    if (t < 32) lk[t] = lv;
    __syncthreads();
    if (t==0){ int b=0; for (int q=0;q<sbid;q++) b += lk[q]; lk[32]=b; }
    __syncthreads();
    int boff = lk[32];
    int run = pre + boff;
    #pragma unroll
    for (int j=0;j<4;j++){
      int idx = idx0+j;
      if (idx < N_NODES){ row_ptr[idx] = run; run += c[j]; }
    }
    if (sbid == SCAN_BLOCKS-1 && t == 0) row_ptr[N_NODES] = boff + total;  // == N_EDGES
    return;
  }
  lin_body<true,false>(x, Wt, b1, nullptr, nullptr, hbf, nullptr, nullptr, N_NODES,
                       blockIdx.x, wlds);
}

// ---------------- fat kernel: layer-0 GEMM (blocks <LB) ∥ CSR scatter (blocks >=LB) ----
__global__ __launch_bounds__(512)
void k_lin_scatter(const unsigned short* __restrict__ hbf,
                   const unsigned short* __restrict__ Wt,
                   const float* __restrict__ avs, const float* __restrict__ avd,
                   void* __restrict__ hp,
                   float* __restrict__ es, float* __restrict__ ed,
                   const int* __restrict__ esrc, const int* __restrict__ edst,
                   const int* __restrict__ rank, const int* __restrict__ row_ptr,
                   int* __restrict__ col_src){
  if ((int)blockIdx.x >= LB){
    int e0 = (blockIdx.x - LB)*512 + threadIdx.x;
    const int stride = (1024 - LB)*512;
    for (int e = e0; e < N_EDGES; e += stride){
      col_src[row_ptr[edst[e]] + rank[e]] = esrc[e];
    }
    return;
  }
  __shared__ unsigned short wlds[128*136];
  lin_body<false,true>(hbf, Wt, nullptr, avs, avd, hp, es, ed, N_NODES, blockIdx.x, wlds);
}

// ---------------- GAT aggregation: fp8 rows, 2-group gather (best measured, R5) --------
// quad q (lane>>4) owns edge t+q; each lane loads uint2 (8B = 8 fp8 features) -> one VMEM
// instruction fetches 4 edge-rows (512B). s/w broadcast via __shfl; acc[8] fp32;
// cross-quad shfl_xor reduce. Aggregate-throughput-bound: deeper unrolls, padding, and
// edge-score precomputes all measured null or negative (R7-R10).
#define AGG_BLOCKS 3126
__global__ __launch_bounds__(256)
void k_gat_agg(const uint2* __restrict__ hp8, const float* __restrict__ es,
               const float* __restrict__ ed, const int* __restrict__ row_ptr,
               const int* __restrict__ col_src, const float* __restrict__ bg,
               unsigned* __restrict__ hbf2){
  int lane = threadIdx.x & 63;
  int sub = lane & 15, quad = lane >> 4;
  int subw = sub << 2;                          // bf16 word offset (residual stream)
  int wav0 = blockIdx.x*4 + (threadIdx.x >> 6);
  const int NW = AGG_BLOCKS*4;

  int i = wav0;
  int start=0, end=0; float esi=0.f, edi=0.f;
  if (i < N_NODES){
    start = row_ptr[i]; end = row_ptr[i+1];
    esi = es[i]; edi = ed[i];
  }
  while (i < N_NODES){
    int inext = i + NW;
    int nstart=0, nend=0; float nes=0.f, ned=0.f;
    if (inext < N_NODES){                       // prefetch next node's scalars
      nstart = row_ptr[inext]; nend = row_ptr[inext+1];
      nes = es[inext]; ned = ed[inext];
    }
    float m0 = leaky(esi + edi);                // self score: softmax recentering
    float acc[8];
    if (quad == 0){                             // self weight exp(0)=1, quad0 only
      uint2 u = hp8[(unsigned)i*16u + sub];
      dec4fp8(u.x, acc); dec4fp8(u.y, acc+4);
    } else {
      #pragma unroll
      for (int r=0;r<8;r++) acc[r]=0.f;
    }
    float zl = (lane==0) ? 1.f : 0.f;

    for (int c0 = start; c0 < end; c0 += 64){
      int j = c0 + lane;
      bool valid = j < end;
      int sreg = valid ? col_src[j] : 0;
      float e = leaky(es[sreg] + edi);
      float w = valid ? __expf(e - m0) : 0.f;   // invalid lanes: w=0 (safe in groups)
      zl += w;
      int len = end - c0; if (len > 64) len = 64;
      int lenp = (len + 3) & ~3;                // round up to whole groups of 4
      int t = 0;
      for (; t + 8 <= lenp; t += 8){            // 2 groups in flight
        int iA = t + quad,          iB = t + 4 + quad;
        int   sA = __shfl(sreg, iA, 64),  sB = __shfl(sreg, iB, 64);
        float wA = __shfl(w,    iA, 64),  wB = __shfl(w,    iB, 64);
        uint2 uA = hp8[(unsigned)sA*16u + sub];
        uint2 uB = hp8[(unsigned)sB*16u + sub];
        float fA[8]; dec4fp8(uA.x, fA); dec4fp8(uA.y, fA+4);
        float fB[8]; dec4fp8(uB.x, fB); dec4fp8(uB.y, fB+4);
        #pragma unroll
        for (int r=0;r<8;r++) acc[r]=fmaf(wA, fA[r], acc[r]);
        #pragma unroll
        for (int r=0;r<8;r++) acc[r]=fmaf(wB, fB[r], acc[r]);
      }
      if (t < lenp){
        int iA = t + quad;
        int   sA = __shfl(sreg, iA, 64);
        float wA = __shfl(w,    iA, 64);
        uint2 uA = hp8[(unsigned)sA*16u + sub];
        float fA[8]; dec4fp8(uA.x, fA); dec4fp8(uA.y, fA+4);
        #pragma unroll
        for (int r=0;r<8;r++) acc[r]=fmaf(wA, fA[r], acc[r]);
      }
    }

    // cross-quad reduce: 4 edge-slots accumulated the same feature set
    #pragma unroll
    for (int r=0;r<8;r++){
      acc[r] += __shfl_xor(acc[r], 16, 64);
      acc[r] += __shfl_xor(acc[r], 32, 64);
    }
    float z = zl;
    #pragma unroll
    for (int off=32; off>0; off>>=1) z += __shfl_xor(z, off, 64);
    float inv = 1.f / z;

    if (quad == 0){
      float4 bgA = *(const float4*)(bg + sub*8);
      float4 bgB = *(const float4*)(bg + sub*8 + 4);
      unsigned base = ((unsigned)i<<6) | subw;
      uint4 ho = *(const uint4*)(hbf2 + base);   // residual (bf16 stream)
      float r0 = fmaf(acc[0], inv, bgA.x); r0 = r0>0.f?r0:0.f; r0 += bf_lo(ho.x);
      float r1 = fmaf(acc[1], inv, bgA.y); r1 = r1>0.f?r1:0.f; r1 += bf_hi(ho.x);
      float r2 = fmaf(acc[2], inv, bgA.z); r2 = r2>0.f?r2:0.f; r2 += bf_lo(ho.y);
      float r3 = fmaf(acc[3], inv, bgA.w); r3 = r3>0.f?r3:0.f; r3 += bf_hi(ho.y);
      float r4 = fmaf(acc[4], inv, bgB.x); r4 = r4>0.f?r4:0.f; r4 += bf_lo(ho.z);
      float r5 = fmaf(acc[5], inv, bgB.y); r5 = r5>0.f?r5:0.f; r5 += bf_hi(ho.z);
      float r6 = fmaf(acc[6], inv, bgB.z); r6 = r6>0.f?r6:0.f; r6 += bf_lo(ho.w);
      float r7 = fmaf(acc[7], inv, bgB.w); r7 = r7>0.f?r7:0.f; r7 += bf_hi(ho.w);
      uint4 pk;
      pk.x = pack2bf(r0,r1); pk.y = pack2bf(r2,r3);
      pk.z = pack2bf(r4,r5); pk.w = pack2bf(r6,r7);
      *(uint4*)(hbf2 + base) = pk;
    }
    i = inext; start = nstart; end = nend; esi = nes; edi = ned;
  }
}

// ---------------- global_add_pool (batch sorted -> run accumulate), bf16 in ------------
__global__ __launch_bounds__(256)
void k_pool(const unsigned* __restrict__ hbf2, const int* __restrict__ batch,
            float* __restrict__ pooled){
  int lane = threadIdx.x & 63, w = threadIdx.x >> 6;
  int n0 = blockIdx.x*128 + w*32;
  if (n0 >= N_NODES) return;
  int nEnd = n0 + 32; if (nEnd > N_NODES) nEnd = N_NODES;
  int cur = batch[n0];
  float a0 = 0.f, a1 = 0.f;
  for (int n = n0; n < nEnd; n++){
    int b = batch[n];
    if (b != cur){
      atomicAdd(&pooled[cur*128 + 2*lane],     a0);
      atomicAdd(&pooled[cur*128 + 2*lane + 1], a1);
      a0 = 0.f; a1 = 0.f; cur = b;
    }
    unsigned u = hbf2[((unsigned)n<<6) | lane];
    a0 += bf_lo(u); a1 += bf_hi(u);
  }
  atomicAdd(&pooled[cur*128 + 2*lane],     a0);
  atomicAdd(&pooled[cur*128 + 2*lane + 1], a1);
}

__global__ void k_final(const float* __restrict__ pooled, const float* __restrict__ W2,
                        const float* __restrict__ b2, float* __restrict__ out){
  int gid = blockIdx.x*256 + threadIdx.x;
  if (gid >= NG*DOUT) return;
  int r = gid >> 6, c = gid & 63;
  float acc = b2[c];
  #pragma unroll 4
  for (int k=0;k<DH;k++) acc = fmaf(pooled[r*DH+k], W2[k*DOUT+c], acc);
  out[(size_t)r*DOUT + c] = acc;
}

extern "C" void kernel_launch(void* const* d_in, const int* in_sizes, int n_in,
                              void* d_out, int out_size, void* d_ws, size_t ws_size,
                              hipStream_t stream){
  const float* x     = (const float*)d_in[0];
  const int*   ei    = (const int*)d_in[1];
  const int*   batch = (const int*)d_in[2];
  const float* W1    = (const float*)d_in[3];
  const float* b1    = (const float*)d_in[4];
  const float* Wg    = (const float*)d_in[5];
  const float* avs   = (const float*)d_in[6];
  const float* avd   = (const float*)d_in[7];
  const float* bgv   = (const float*)d_in[8];
  const float* W2    = (const float*)d_in[9];
  const float* b2    = (const float*)d_in[10];
  float* out = (float*)d_out;

  char* ws = (char*)d_ws;
  unsigned short* hbf = (unsigned short*)ws;       ws += (size_t)N_NODES*DH*2;   // residual stream (bf16)
  void* hp        = (void*)ws;                     ws += (size_t)N_NODES*DH;     // GEMM out (fp8 e4m3)
  float* es       = (float*)ws;                    ws += (size_t)N_NODES*4;
  float* ed       = (float*)ws;                    ws += (size_t)N_NODES*4;
  float* pooled   = (float*)ws;                    ws += NG*DH*4;
  unsigned short* Wt = (unsigned short*)ws;        ws += 4*16384*2;
  int* counts     = (int*)ws;                      ws += (size_t)N_NODES*4;      // counts+bsum: one memset
  int* bsum       = (int*)ws;                      ws += 64*4;
  int* row_ptr    = (int*)ws;                      ws += ((size_t)N_NODES+1)*4;
  int* rank       = (int*)ws;                      ws += (size_t)N_EDGES*4;
  int* col_src    = (int*)ws;                      ws += (size_t)N_EDGES*4;

  const int* esrc = ei;
  const int* edst = ei + N_EDGES;

  hipMemsetAsync(counts, 0, (N_NODES + 64)*sizeof(int), stream);

  // K1: edge histogram + weight transpose/cast + pooled zero
  k_hist<<<1024, 256, 0, stream>>>(edst, counts, rank, W1, Wg, Wt, pooled);
  // K2: mlp1 GEMM (391 blocks) ∥ full row_ptr scan via decoupled lookback (25 blocks)
  k_lin1_scan<<<LB + SCAN_BLOCKS, 512, 0, stream>>>(x, Wt, b1, hbf, counts, bsum, row_ptr);
  // K3: layer-0 GEMM + es/ed (391 blocks) ∥ CSR scatter (633 blocks)
  k_lin_scatter<<<1024, 512, 0, stream>>>(hbf, Wt + 16384, avs, avd,
                                          hp, es, ed, esrc, edst, rank, row_ptr, col_src);
  // K4: layer-0 aggregation (fp8 gather)
  k_gat_agg<<<AGG_BLOCKS, 256, 0, stream>>>((const uint2*)hp, es, ed,
                                            row_ptr, col_src, bgv, (unsigned*)hbf);
  // layers 1,2
  for (int l = 1; l < 3; l++){
    k_linear_mfma<false,true><<<LB, 512, 0, stream>>>(hbf, Wt + (size_t)(l+1)*16384, nullptr,
                                                      avs + l*DH, avd + l*DH,
                                                      hp, es, ed, N_NODES);
    k_gat_agg<<<AGG_BLOCKS, 256, 0, stream>>>((const uint2*)hp, es, ed,
                                              row_ptr, col_src, bgv + l*DH,
                                              (unsigned*)hbf);
  }
  // K9: pool (391 blocks, run-accumulate, ~100k atomics) + K10: final linear
  k_pool<<<(N_NODES+127)/128, 256, 0, stream>>>((const unsigned*)hbf, batch, pooled);
  k_final<<<(NG*DOUT+255)/256, 256, 0, stream>>>(pooled, W2, b2, out);
}